// Round 21
// baseline (134.040 us; speedup 1.0000x reference)
//
#include <hip/hip_runtime.h>
#include <hip/hip_bf16.h>

typedef __attribute__((ext_vector_type(8))) short short8;
typedef __attribute__((ext_vector_type(4))) short s16x4;
typedef __attribute__((ext_vector_type(4))) float f32x4;
typedef __hip_bfloat16 bf16;

#define NB 2
#define NS 2048
#define ND 1024
#define NH 16
#define NE 64

// Q pre-scale: 1/sqrt(64) * log2(e), so attn softmax uses exp2 directly.
#define QSCALE 0.1803368867f

// async global->LDS, 16B per lane; LDS dest = wave-uniform base + lane*16
#define ASYNC16(g, l) __builtin_amdgcn_global_load_lds( \
    (const __attribute__((address_space(1))) void*)(g), \
    (__attribute__((address_space(3))) void*)(l), 16, 0, 0)

__device__ __forceinline__ unsigned short bf16b(float x) {
  __hip_bfloat16 h = __float2bfloat16(x);
  unsigned short u;
  __builtin_memcpy(&u, &h, 2);
  return u;
}

// ---------------------------------------------------------------------------
// Merged prep: blocks 0..2047 ingest x, 2048..2559 ingest Wproj,
// 2560..3327 transpose Wq/Wk/Wv -> WT[w][h][e][k] (f32 -> bf16).
// ---------------------------------------------------------------------------
__global__ __launch_bounds__(256) void prep_all(const float* __restrict__ x,
                                                bf16* __restrict__ xb,
                                                const float* __restrict__ wp,
                                                bf16* __restrict__ wpb,
                                                const float* __restrict__ Wq,
                                                const float* __restrict__ Wk,
                                                const float* __restrict__ Wv,
                                                bf16* __restrict__ WT) {
  const int bid = blockIdx.x;
  const int tid = threadIdx.x;
  if (bid < 2560) {
    const float* src;
    bf16* dst;
    int i;
    if (bid < 2048) { src = x;  dst = xb;  i = (bid * 256 + tid) * 8; }
    else            { src = wp; dst = wpb; i = ((bid - 2048) * 256 + tid) * 8; }
    const float4 a = *(const float4*)(src + i);
    const float4 b = *(const float4*)(src + i + 4);
    *(ushort4*)(dst + i)     = make_ushort4(bf16b(a.x), bf16b(a.y), bf16b(a.z), bf16b(a.w));
    *(ushort4*)(dst + i + 4) = make_ushort4(bf16b(b.x), bf16b(b.y), bf16b(b.z), bf16b(b.w));
    return;
  }
  const int tb = bid - 2560;              // 0..767
  const int w = tb >> 8;                  // 0..2
  const int xx = tb & 255;                // h*16 + kt
  const float* W = (w == 0) ? Wq : ((w == 1) ? Wk : Wv);
  const int h = xx >> 4, kt = xx & 15;
  __shared__ bf16 tile[64][65];
#pragma unroll
  for (int i = 0; i < 16; ++i) {
    const int idx = i * 256 + tid, kl = idx >> 6, e = idx & 63;
    tile[kl][e] = __float2bfloat16(W[((size_t)h * ND + kt * 64 + kl) * NE + e]);
  }
  __syncthreads();
#pragma unroll
  for (int i = 0; i < 16; ++i) {
    const int idx = i * 256 + tid, el = idx >> 6, kl = idx & 63;
    WT[((size_t)w * NH * NE + h * NE + el) * ND + kt * 64 + kl] = tile[kl][el];
  }
}

// ---------------------------------------------------------------------------
// QKV projection, 2-phase double-buffered. Conflict-free LDS swizzle
// f(R)=(R>>1)&3. grid (8, 32, 3); tile 128x128; BK=32.
// ---------------------------------------------------------------------------
__global__ __launch_bounds__(256) void qkv_gemm(const bf16* __restrict__ X,
                                                const bf16* __restrict__ WT,
                                                bf16* __restrict__ Qo,
                                                bf16* __restrict__ Ko,
                                                bf16* __restrict__ Vo) {
  const int w = blockIdx.z;
  const bf16* Bm = WT + (size_t)w * (NH * NE * ND);
  const int n0 = blockIdx.x * 128, m0 = blockIdx.y * 128;
  __shared__ __align__(16) bf16 As[2][128 * 32];
  __shared__ __align__(16) bf16 Bs[2][128 * 32];
  const int tid = threadIdx.x;
  const int lane = tid & 63, wid = tid >> 6;
  const int wm = wid >> 1, wn = wid & 1;
  const int g = lane >> 4, c = lane & 15;
  const int row4 = tid >> 2;
  const int kcs = ((tid & 3) ^ ((tid >> 3) & 3)) * 8;   // src chunk: f(R)=(R>>1)&3

  auto stage = [&](int buf, int k0) {
    ASYNC16(X + (size_t)(m0 + row4) * ND + k0 + kcs, As[buf] + wid * 512);
    ASYNC16(X + (size_t)(m0 + 64 + row4) * ND + k0 + kcs, As[buf] + 2048 + wid * 512);
    ASYNC16(Bm + (size_t)(n0 + row4) * ND + k0 + kcs, Bs[buf] + wid * 512);
    ASYNC16(Bm + (size_t)(n0 + 64 + row4) * ND + k0 + kcs, Bs[buf] + 2048 + wid * 512);
  };

  f32x4 acc[4][4] = {};
  stage(0, 0);
  __syncthreads();
  int cur = 0;
  for (int k0 = 0; k0 < ND; k0 += 32) {
    if (k0 + 32 < ND) stage(cur ^ 1, k0 + 32);   // prefetch overlaps compute
    const short* as = (const short*)As[cur];
    const short* bs = (const short*)Bs[cur];
    short8 af[4], bq[4];
#pragma unroll
    for (int i = 0; i < 4; ++i)
      af[i] = *(const short8*)&as[(wm * 64 + i * 16 + c) * 32 + ((g ^ ((c >> 1) & 3)) * 8)];
#pragma unroll
    for (int j = 0; j < 4; ++j)
      bq[j] = *(const short8*)&bs[(wn * 64 + j * 16 + c) * 32 + ((g ^ ((c >> 1) & 3)) * 8)];
    __builtin_amdgcn_s_setprio(1);
#pragma unroll
    for (int i = 0; i < 4; ++i)
#pragma unroll
      for (int j = 0; j < 4; ++j)
        acc[i][j] = __builtin_amdgcn_mfma_f32_16x16x32_bf16(af[i], bq[j], acc[i][j], 0, 0, 0);
    __builtin_amdgcn_s_setprio(0);
    __syncthreads();   // drains prefetch; publishes buffers
    cur ^= 1;
  }
  const float osc = (w == 0) ? QSCALE : 1.0f;
#pragma unroll
  for (int i = 0; i < 4; ++i) {
    const int mg0 = m0 + wm * 64 + i * 16 + g * 4;
#pragma unroll
    for (int j = 0; j < 4; ++j) {
      const int ng = n0 + wn * 64 + j * 16 + c;
      const int h = ng >> 6, e = ng & 63;
      if (w == 2) {
        const int b = mg0 >> 11, s = mg0 & 2047;
        ushort4 pk = make_ushort4(bf16b(acc[i][j][0]), bf16b(acc[i][j][1]),
                                  bf16b(acc[i][j][2]), bf16b(acc[i][j][3]));
        *(ushort4*)&Vo[(((size_t)b * NH + h) * NE + e) * NS + s] = pk;
      } else {
        bf16* O = (w == 0) ? Qo : Ko;
#pragma unroll
        for (int r = 0; r < 4; ++r) {
          const int m = mg0 + r, b = m >> 11, s = m & 2047;
          O[(((size_t)b * NH + h) * NS + s) * NE + e] = __float2bfloat16(acc[i][j][r] * osc);
        }
      }
    }
  }
}

// ---------------------------------------------------------------------------
// Flash attention (causal), v11: QBLK=128 (each wave owns TWO 16-row
// q-blocks: rows q0+64*qm+wid*16+..), KVBLK=64. K/V staged once per tile
// serves both halves (bk reads shared). Last tile skipped for the lower half
// (fully masked). Ps reused serially per half. Balanced map qt=jj<8?jj:23-jj
// -> every CU's 2 blocks total exactly 34 tile-iters. grid (32 bh, 16 jj).
// ---------------------------------------------------------------------------
__global__ __launch_bounds__(256, 2) void attn_fwd(const bf16* __restrict__ Qb,
                                                   const bf16* __restrict__ Kb,
                                                   const bf16* __restrict__ Vt,
                                                   bf16* __restrict__ AO) {
  const int bh = blockIdx.x;
  const int jj = blockIdx.y;                  // 0..15
  const int qt = (jj < 8) ? jj : 23 - jj;     // 128-row q-tile index, balanced
  const int q0 = qt * 128;
  __shared__ __align__(16) bf16 Ks[2][64 * 64];
  __shared__ __align__(16) bf16 Vs[2][64 * 64];
  __shared__ __align__(16) bf16 Ps[4][16 * 64];
  const int tid = threadIdx.x, lane = tid & 63, wid = tid >> 6;
  const int g = lane >> 4, c = lane & 15;
  const int sw8 = ((tid & 7) ^ ((tid >> 3) & 7)) * 8;  // staged source chunk
  const bf16* Qg = Qb + (size_t)bh * NS * NE;
  const bf16* Kg = Kb + (size_t)bh * NS * NE;
  const bf16* Vg = Vt + (size_t)bh * NE * NS;
  const int b = bh >> 4, h = bh & 15;

  const short8 bones = {0x3F80, 0x3F80, 0x3F80, 0x3F80, 0x3F80, 0x3F80, 0x3F80, 0x3F80};

  short8 aq[2][2];   // [qm][kk]: lane supplies Q[q0+64*qm+wid*16+c][...]
#pragma unroll
  for (int qm = 0; qm < 2; ++qm)
#pragma unroll
    for (int kk = 0; kk < 2; ++kk)
      aq[qm][kk] = *(const short8*)&Qg[(size_t)(q0 + 64 * qm + wid * 16 + c) * NE + kk * 32 + g * 8];

  f32x4 acc_o[2][4] = {};
  f32x4 acc_l[2] = {};
  float mrun[2] = {-1.0e30f, -1.0e30f};

  auto stage = [&](int buf, int t0) {
    ASYNC16(Kg + (size_t)(t0 + (tid >> 3)) * NE + sw8,      Ks[buf] + wid * 512);
    ASYNC16(Kg + (size_t)(t0 + 32 + (tid >> 3)) * NE + sw8, Ks[buf] + 2048 + wid * 512);
    ASYNC16(Vg + (size_t)(tid >> 3) * NS + t0 + sw8,        Vs[buf] + wid * 512);
    ASYNC16(Vg + (size_t)(32 + (tid >> 3)) * NS + t0 + sw8, Vs[buf] + 2048 + wid * 512);
  };

  const int nt = 2 * qt + 2;                  // 64-token tiles for the upper half
  int cur = 0;
  stage(0, 0);
  __syncthreads();
  for (int tt = 0; tt < nt; ++tt) {
    const int t0 = tt * 64;
    if (tt + 1 < nt) stage(cur ^ 1, t0 + 64);   // async prefetch overlaps compute
    const short* ks = (const short*)Ks[cur];
    const short* vs = (const short*)Vs[cur];
    // shared K fragments for both halves
    short8 bk[2][4];
    __builtin_amdgcn_s_setprio(1);
#pragma unroll
    for (int kk = 0; kk < 2; ++kk)
#pragma unroll
      for (int tn = 0; tn < 4; ++tn)
        bk[kk][tn] = *(const short8*)&ks[(tn * 16 + c) * 64 + (((kk * 4 + g) ^ (c & 7)) * 8)];
    __builtin_amdgcn_s_setprio(0);
#pragma unroll
    for (int qm = 0; qm < 2; ++qm) {
      if (qm == 0 && tt == nt - 1) continue;   // lower half: last tile fully masked
      const bool diag = (tt >= nt - 2 + qm);   // this half's diagonal tile
      // --- QK^T, swapped: D[token][qrow] ---
      f32x4 sacc[4] = {};
      __builtin_amdgcn_s_setprio(1);
#pragma unroll
      for (int kk = 0; kk < 2; ++kk)
#pragma unroll
        for (int tn = 0; tn < 4; ++tn)
          sacc[tn] = __builtin_amdgcn_mfma_f32_16x16x32_bf16(bk[kk][tn], aq[qm][kk], sacc[tn], 0, 0, 0);
      __builtin_amdgcn_s_setprio(0);
      // --- softmax: lane owns q-row c of this half; max is lane-local ---
      float mx = -1.0e30f;
#pragma unroll
      for (int tn = 0; tn < 4; ++tn) {
#pragma unroll
        for (int r = 0; r < 4; ++r) {
          float v = sacc[tn][r];
          if (diag) {
            const int tcol = t0 + tn * 16 + g * 4 + r;
            const int qrow = q0 + 64 * qm + wid * 16 + c;
            v = (tcol <= qrow) ? v : -1.0e30f;
            sacc[tn][r] = v;
          }
          mx = fmaxf(mx, v);
        }
      }
      if (__any(mx > mrun[qm] + 8.0f)) {
        mx = fmaxf(mx, __shfl_xor(mx, 16));
        mx = fmaxf(mx, __shfl_xor(mx, 32));
        const float mnew = fmaxf(mrun[qm], mx);
        const float alpha = __builtin_exp2f(mrun[qm] - mnew);
        mrun[qm] = mnew;
        float al[4];
#pragma unroll
        for (int r = 0; r < 4; ++r) al[r] = __shfl(alpha, g * 4 + r);
#pragma unroll
        for (int fe = 0; fe < 4; ++fe)
#pragma unroll
          for (int r = 0; r < 4; ++r) acc_o[qm][fe][r] *= al[r];
#pragma unroll
        for (int r = 0; r < 4; ++r) acc_l[qm][r] *= al[r];
      }
      // --- P = exp2(s - mrun) -> wave-private LDS (reused per half) ---
      short* psw = (short*)Ps[wid];
#pragma unroll
      for (int tn = 0; tn < 4; ++tn) {
        s16x4 pw;
#pragma unroll
        for (int r = 0; r < 4; ++r)
          pw[r] = (short)bf16b(__builtin_exp2f(sacc[tn][r] - mrun[qm]));
        const int blk = (2 * tn + (g >> 1)) ^ (c & 7);
        *(s16x4*)&psw[c * 64 + blk * 8 + (g & 1) * 4] = pw;
      }
      // --- PV + row-sum MFMA ---
      const short* ps = (const short*)Ps[wid];
      __builtin_amdgcn_s_setprio(1);
#pragma unroll
      for (int ks2 = 0; ks2 < 2; ++ks2) {
        short8 ap, bv[4];
        ap = *(const short8*)&ps[c * 64 + (((ks2 * 4 + g) ^ (c & 7)) * 8)];
        acc_l[qm] = __builtin_amdgcn_mfma_f32_16x16x32_bf16(ap, bones, acc_l[qm], 0, 0, 0);
#pragma unroll
        for (int fe = 0; fe < 4; ++fe)
          bv[fe] = *(const short8*)&vs[(fe * 16 + c) * 64 + (((ks2 * 4 + g) ^ (c & 7)) * 8)];
#pragma unroll
        for (int fe = 0; fe < 4; ++fe)
          acc_o[qm][fe] = __builtin_amdgcn_mfma_f32_16x16x32_bf16(ap, bv[fe], acc_o[qm][fe], 0, 0, 0);
      }
      __builtin_amdgcn_s_setprio(0);
    }
    __syncthreads();   // drains prefetch (vmcnt0) + publishes buffers
    cur ^= 1;
  }
#pragma unroll
  for (int qm = 0; qm < 2; ++qm)
#pragma unroll
    for (int fe = 0; fe < 4; ++fe)
#pragma unroll
      for (int r = 0; r < 4; ++r) {
        const int s = q0 + 64 * qm + wid * 16 + g * 4 + r;
        const float val = acc_o[qm][fe][r] / acc_l[qm][r];
        AO[((size_t)b * NS + s) * ND + h * NE + fe * 16 + c] = __float2bfloat16(val);
      }
}

// ---------------------------------------------------------------------------
// Output projection, 2-phase double-buffered, conflict-free swizzle.
// grid (8, 32).
// ---------------------------------------------------------------------------
__global__ __launch_bounds__(256) void proj_gemm(const bf16* __restrict__ A,
                                                 const bf16* __restrict__ Wp,
                                                 float* __restrict__ Y) {
  const int n0 = blockIdx.x * 128, m0 = blockIdx.y * 128;
  __shared__ __align__(16) bf16 As[2][128 * 32];
  __shared__ __align__(16) bf16 Bs[2][128 * 32];
  const int tid = threadIdx.x;
  const int lane = tid & 63, wid = tid >> 6;
  const int wm = wid >> 1, wn = wid & 1;
  const int g = lane >> 4, c = lane & 15;
  const int row4 = tid >> 2;
  const int kcs = ((tid & 3) ^ ((tid >> 3) & 3)) * 8;

  auto stage = [&](int buf, int k0) {
    ASYNC16(A + (size_t)(m0 + row4) * ND + k0 + kcs, As[buf] + wid * 512);
    ASYNC16(A + (size_t)(m0 + 64 + row4) * ND + k0 + kcs, As[buf] + 2048 + wid * 512);
    ASYNC16(Wp + (size_t)(n0 + row4) * ND + k0 + kcs, Bs[buf] + wid * 512);
    ASYNC16(Wp + (size_t)(n0 + 64 + row4) * ND + k0 + kcs, Bs[buf] + 2048 + wid * 512);
  };

  f32x4 acc[4][4] = {};
  stage(0, 0);
  __syncthreads();
  int cur = 0;
  for (int k0 = 0; k0 < ND; k0 += 32) {
    if (k0 + 32 < ND) stage(cur ^ 1, k0 + 32);
    const short* as = (const short*)As[cur];
    const short* bs = (const short*)Bs[cur];
    short8 af[4], bq[4];
#pragma unroll
    for (int i = 0; i < 4; ++i)
      af[i] = *(const short8*)&as[(wm * 64 + i * 16 + c) * 32 + ((g ^ ((c >> 1) & 3)) * 8)];
#pragma unroll
    for (int j = 0; j < 4; ++j)
      bq[j] = *(const short8*)&bs[(wn * 64 + j * 16 + c) * 32 + ((g ^ ((c >> 1) & 3)) * 8)];
    __builtin_amdgcn_s_setprio(1);
#pragma unroll
    for (int i = 0; i < 4; ++i)
#pragma unroll
      for (int j = 0; j < 4; ++j)
        acc[i][j] = __builtin_amdgcn_mfma_f32_16x16x32_bf16(af[i], bq[j], acc[i][j], 0, 0, 0);
    __builtin_amdgcn_s_setprio(0);
    __syncthreads();
    cur ^= 1;
  }
#pragma unroll
  for (int i = 0; i < 4; ++i) {
    const int mg0 = m0 + wm * 64 + i * 16 + g * 4;
#pragma unroll
    for (int j = 0; j < 4; ++j) {
      const int ng = n0 + wn * 64 + j * 16 + c;
#pragma unroll
      for (int r = 0; r < 4; ++r)
        Y[(size_t)(mg0 + r) * ND + ng] = acc[i][j][r];
    }
  }
}

extern "C" void kernel_launch(void* const* d_in, const int* in_sizes, int n_in,
                              void* d_out, int out_size, void* d_ws, size_t ws_size,
                              hipStream_t stream) {
  const float* x  = (const float*)d_in[0];
  const float* Wq = (const float*)d_in[1];
  const float* Wk = (const float*)d_in[2];
  const float* Wv = (const float*)d_in[3];
  const float* Wp = (const float*)d_in[4];
  float* out = (float*)d_out;            // f32 output (round-7 verified)

  bf16* ws = (bf16*)d_ws;
  bf16* Xb  = ws;                                   // B*S*D     4,194,304
  bf16* WT  = Xb + (size_t)NB * NS * ND;            // 3*H*E*D   3,145,728
  bf16* Wpb = WT + (size_t)3 * NH * NE * ND;        // D*D       1,048,576
  bf16* Qb  = Wpb + (size_t)ND * ND;                // B*H*S*E   4,194,304 each
  bf16* Kb  = Qb + (size_t)NB * NH * NS * NE;
  bf16* Vt  = Kb + (size_t)NB * NH * NS * NE;
  bf16* AO  = Vt + (size_t)NB * NH * NS * NE;

  hipLaunchKernelGGL(prep_all, dim3(3328), dim3(256), 0, stream,
                     x, Xb, Wp, Wpb, Wq, Wk, Wv, WT);
  hipLaunchKernelGGL(qkv_gemm, dim3(8, 32, 3), dim3(256), 0, stream, Xb, WT, Qb, Kb, Vt);
  hipLaunchKernelGGL(attn_fwd, dim3(32, 16), dim3(256), 0, stream, Qb, Kb, Vt, AO);
  hipLaunchKernelGGL(proj_gemm, dim3(8, 32), dim3(256), 0, stream, AO, Wpb, out);
}

// Round 22
// 104.867 us; speedup vs baseline: 1.2782x; 1.2782x over previous
//
#include <hip/hip_runtime.h>
#include <hip/hip_bf16.h>

typedef __attribute__((ext_vector_type(8))) short short8;
typedef __attribute__((ext_vector_type(4))) short s16x4;
typedef __attribute__((ext_vector_type(4))) float f32x4;
typedef __hip_bfloat16 bf16;

#define NB 2
#define NS 2048
#define ND 1024
#define NH 16
#define NE 64

// Q pre-scale: 1/sqrt(64) * log2(e), so attn softmax uses exp2 directly.
#define QSCALE 0.1803368867f

// async global->LDS, 16B per lane; LDS dest = wave-uniform base + lane*16
#define ASYNC16(g, l) __builtin_amdgcn_global_load_lds( \
    (const __attribute__((address_space(1))) void*)(g), \
    (__attribute__((address_space(3))) void*)(l), 16, 0, 0)

__device__ __forceinline__ unsigned short bf16b(float x) {
  __hip_bfloat16 h = __float2bfloat16(x);
  unsigned short u;
  __builtin_memcpy(&u, &h, 2);
  return u;
}

// ---------------------------------------------------------------------------
// Merged prep: blocks 0..2047 ingest x, 2048..2559 ingest Wproj,
// 2560..3327 transpose Wq/Wk/Wv -> WT[w][h][e][k] (f32 -> bf16).
// ---------------------------------------------------------------------------
__global__ __launch_bounds__(256) void prep_all(const float* __restrict__ x,
                                                bf16* __restrict__ xb,
                                                const float* __restrict__ wp,
                                                bf16* __restrict__ wpb,
                                                const float* __restrict__ Wq,
                                                const float* __restrict__ Wk,
                                                const float* __restrict__ Wv,
                                                bf16* __restrict__ WT) {
  const int bid = blockIdx.x;
  const int tid = threadIdx.x;
  if (bid < 2560) {
    const float* src;
    bf16* dst;
    int i;
    if (bid < 2048) { src = x;  dst = xb;  i = (bid * 256 + tid) * 8; }
    else            { src = wp; dst = wpb; i = ((bid - 2048) * 256 + tid) * 8; }
    const float4 a = *(const float4*)(src + i);
    const float4 b = *(const float4*)(src + i + 4);
    *(ushort4*)(dst + i)     = make_ushort4(bf16b(a.x), bf16b(a.y), bf16b(a.z), bf16b(a.w));
    *(ushort4*)(dst + i + 4) = make_ushort4(bf16b(b.x), bf16b(b.y), bf16b(b.z), bf16b(b.w));
    return;
  }
  const int tb = bid - 2560;              // 0..767
  const int w = tb >> 8;                  // 0..2
  const int xx = tb & 255;                // h*16 + kt
  const float* W = (w == 0) ? Wq : ((w == 1) ? Wk : Wv);
  const int h = xx >> 4, kt = xx & 15;
  __shared__ bf16 tile[64][65];
#pragma unroll
  for (int i = 0; i < 16; ++i) {
    const int idx = i * 256 + tid, kl = idx >> 6, e = idx & 63;
    tile[kl][e] = __float2bfloat16(W[((size_t)h * ND + kt * 64 + kl) * NE + e]);
  }
  __syncthreads();
#pragma unroll
  for (int i = 0; i < 16; ++i) {
    const int idx = i * 256 + tid, el = idx >> 6, kl = idx & 63;
    WT[((size_t)w * NH * NE + h * NE + el) * ND + kt * 64 + kl] = tile[kl][el];
  }
}

// ---------------------------------------------------------------------------
// QKV projection, 2-phase double-buffered, conflict-free LDS swizzle
// f(R)=(R>>1)&3, T1 XCD-contiguous tile remap: t=(id%8)*32+id/8 gives each
// XCD 4 m-panels x 8 n-tiles (~3MB < 4MB L2). grid (8, 32, 3); BK=32.
// ---------------------------------------------------------------------------
__global__ __launch_bounds__(256) void qkv_gemm(const bf16* __restrict__ X,
                                                const bf16* __restrict__ WT,
                                                bf16* __restrict__ Qo,
                                                bf16* __restrict__ Ko,
                                                bf16* __restrict__ Vo) {
  const int w = blockIdx.z;
  const bf16* Bm = WT + (size_t)w * (NH * NE * ND);
  const int id = blockIdx.x + 8 * blockIdx.y;          // 0..255 within this w
  const int t = (id & 7) * 32 + (id >> 3);             // XCD-contiguous remap
  const int n0 = (t & 7) * 128, m0 = (t >> 3) * 128;
  __shared__ __align__(16) bf16 As[2][128 * 32];
  __shared__ __align__(16) bf16 Bs[2][128 * 32];
  const int tid = threadIdx.x;
  const int lane = tid & 63, wid = tid >> 6;
  const int wm = wid >> 1, wn = wid & 1;
  const int g = lane >> 4, c = lane & 15;
  const int row4 = tid >> 2;
  const int kcs = ((tid & 3) ^ ((tid >> 3) & 3)) * 8;  // src chunk: f(R)=(R>>1)&3

  auto stage = [&](int buf, int k0) {
    ASYNC16(X + (size_t)(m0 + row4) * ND + k0 + kcs, As[buf] + wid * 512);
    ASYNC16(X + (size_t)(m0 + 64 + row4) * ND + k0 + kcs, As[buf] + 2048 + wid * 512);
    ASYNC16(Bm + (size_t)(n0 + row4) * ND + k0 + kcs, Bs[buf] + wid * 512);
    ASYNC16(Bm + (size_t)(n0 + 64 + row4) * ND + k0 + kcs, Bs[buf] + 2048 + wid * 512);
  };

  f32x4 acc[4][4] = {};
  stage(0, 0);
  __syncthreads();
  int cur = 0;
  for (int k0 = 0; k0 < ND; k0 += 32) {
    if (k0 + 32 < ND) stage(cur ^ 1, k0 + 32);   // prefetch overlaps compute
    const short* as = (const short*)As[cur];
    const short* bs = (const short*)Bs[cur];
    short8 af[4], bq[4];
#pragma unroll
    for (int i = 0; i < 4; ++i)
      af[i] = *(const short8*)&as[(wm * 64 + i * 16 + c) * 32 + ((g ^ ((c >> 1) & 3)) * 8)];
#pragma unroll
    for (int j = 0; j < 4; ++j)
      bq[j] = *(const short8*)&bs[(wn * 64 + j * 16 + c) * 32 + ((g ^ ((c >> 1) & 3)) * 8)];
    __builtin_amdgcn_s_setprio(1);
#pragma unroll
    for (int i = 0; i < 4; ++i)
#pragma unroll
      for (int j = 0; j < 4; ++j)
        acc[i][j] = __builtin_amdgcn_mfma_f32_16x16x32_bf16(af[i], bq[j], acc[i][j], 0, 0, 0);
    __builtin_amdgcn_s_setprio(0);
    __syncthreads();   // drains prefetch; publishes buffers
    cur ^= 1;
  }
  const float osc = (w == 0) ? QSCALE : 1.0f;
#pragma unroll
  for (int i = 0; i < 4; ++i) {
    const int mg0 = m0 + wm * 64 + i * 16 + g * 4;
#pragma unroll
    for (int j = 0; j < 4; ++j) {
      const int ng = n0 + wn * 64 + j * 16 + c;
      const int h = ng >> 6, e = ng & 63;
      if (w == 2) {
        const int b = mg0 >> 11, s = mg0 & 2047;
        ushort4 pk = make_ushort4(bf16b(acc[i][j][0]), bf16b(acc[i][j][1]),
                                  bf16b(acc[i][j][2]), bf16b(acc[i][j][3]));
        *(ushort4*)&Vo[(((size_t)b * NH + h) * NE + e) * NS + s] = pk;
      } else {
        bf16* O = (w == 0) ? Qo : Ko;
#pragma unroll
        for (int r = 0; r < 4; ++r) {
          const int m = mg0 + r, b = m >> 11, s = m & 2047;
          O[(((size_t)b * NH + h) * NS + s) * NE + e] = __float2bfloat16(acc[i][j][r] * osc);
        }
      }
    }
  }
}

// ---------------------------------------------------------------------------
// Flash attention (causal), v7 (round-18 measured best, 48.4us): 4-wave
// blocks, QBLK=64, KVBLK=64, double-buffered 2-phase pipeline; swapped QK^T;
// lane-local max; defer-max THR=8; ones-MFMA row-sum; balanced qt map.
// grid (32 bh, 32 qi).
// ---------------------------------------------------------------------------
__global__ __launch_bounds__(256, 4) void attn_fwd(const bf16* __restrict__ Qb,
                                                   const bf16* __restrict__ Kb,
                                                   const bf16* __restrict__ Vt,
                                                   bf16* __restrict__ AO) {
  const int bh = blockIdx.x;
  const int qi = blockIdx.y;
  const int a = qi & 7, k = qi >> 3;
  const int qt = (k == 0) ? a : (k == 1) ? 31 - a : (k == 2) ? a + 8 : 23 - a;
  const int q0 = qt * 64;
  __shared__ __align__(16) bf16 Ks[2][64 * 64];
  __shared__ __align__(16) bf16 Vs[2][64 * 64];
  __shared__ __align__(16) bf16 Ps[4][16 * 64];
  const int tid = threadIdx.x, lane = tid & 63, wid = tid >> 6;
  const int g = lane >> 4, c = lane & 15;
  const int sw8 = ((tid & 7) ^ ((tid >> 3) & 7)) * 8;  // staged source chunk
  const bf16* Qg = Qb + (size_t)bh * NS * NE;
  const bf16* Kg = Kb + (size_t)bh * NS * NE;
  const bf16* Vg = Vt + (size_t)bh * NE * NS;

  short8 aq[2];   // lane supplies Q[qrow=c][k]
#pragma unroll
  for (int kk = 0; kk < 2; ++kk)
    aq[kk] = *(const short8*)&Qg[(size_t)(q0 + wid * 16 + c) * NE + kk * 32 + g * 8];

  const short8 bones = {0x3F80, 0x3F80, 0x3F80, 0x3F80, 0x3F80, 0x3F80, 0x3F80, 0x3F80};

  f32x4 acc_o[4] = {};
  f32x4 acc_l = {};
  float mrun = -1.0e30f;   // per-lane: running max of q-row c

  auto stage = [&](int buf, int t0) {
    ASYNC16(Kg + (size_t)(t0 + (tid >> 3)) * NE + sw8,      Ks[buf] + wid * 512);
    ASYNC16(Kg + (size_t)(t0 + 32 + (tid >> 3)) * NE + sw8, Ks[buf] + 2048 + wid * 512);
    ASYNC16(Vg + (size_t)(tid >> 3) * NS + t0 + sw8,        Vs[buf] + wid * 512);
    ASYNC16(Vg + (size_t)(32 + (tid >> 3)) * NS + t0 + sw8, Vs[buf] + 2048 + wid * 512);
  };

  const int nt = qt + 1;
  int cur = 0;
  stage(0, 0);
  __syncthreads();
  for (int tt = 0; tt < nt; ++tt) {
    const int t0 = tt * 64;
    if (tt + 1 < nt) stage(cur ^ 1, t0 + 64);   // async prefetch overlaps compute
    const bool diag = (tt == nt - 1);
    // --- QK^T, swapped: D[token][qrow]; row=4g+r=token-in-16, col=c=qrow ---
    f32x4 sacc[4] = {};
    const short* ks = (const short*)Ks[cur];
    const short* vs = (const short*)Vs[cur];
    __builtin_amdgcn_s_setprio(1);
#pragma unroll
    for (int kk = 0; kk < 2; ++kk) {
      short8 bk[4];
#pragma unroll
      for (int tn = 0; tn < 4; ++tn)
        bk[tn] = *(const short8*)&ks[(tn * 16 + c) * 64 + (((kk * 4 + g) ^ (c & 7)) * 8)];
#pragma unroll
      for (int tn = 0; tn < 4; ++tn)
        sacc[tn] = __builtin_amdgcn_mfma_f32_16x16x32_bf16(bk[tn], aq[kk], sacc[tn], 0, 0, 0);
    }
    __builtin_amdgcn_s_setprio(0);
    // --- softmax: lane owns q-row c; max is lane-local ---
    float mx = -1.0e30f;
#pragma unroll
    for (int tn = 0; tn < 4; ++tn) {
#pragma unroll
      for (int r = 0; r < 4; ++r) {
        float v = sacc[tn][r];
        if (diag) {
          const int tcol = t0 + tn * 16 + g * 4 + r;        // token index
          const int qrow = q0 + wid * 16 + c;
          v = (tcol <= qrow) ? v : -1.0e30f;
          sacc[tn][r] = v;
        }
        mx = fmaxf(mx, v);
      }
    }
    if (__any(mx > mrun + 8.0f)) {
      mx = fmaxf(mx, __shfl_xor(mx, 16));
      mx = fmaxf(mx, __shfl_xor(mx, 32));
      const float mnew = fmaxf(mrun, mx);
      const float alpha = __builtin_exp2f(mrun - mnew);
      mrun = mnew;
      float al[4];
#pragma unroll
      for (int r = 0; r < 4; ++r) al[r] = __shfl(alpha, g * 4 + r);
#pragma unroll
      for (int fe = 0; fe < 4; ++fe)
#pragma unroll
        for (int r = 0; r < 4; ++r) acc_o[fe][r] *= al[r];
#pragma unroll
      for (int r = 0; r < 4; ++r) acc_l[r] *= al[r];
    }
    // --- P = exp2(s - mrun) -> LDS rows [qrow=c][token], 4x b64, swizzled ---
    short* psw = (short*)Ps[wid];
#pragma unroll
    for (int tn = 0; tn < 4; ++tn) {
      s16x4 pw;
#pragma unroll
      for (int r = 0; r < 4; ++r)
        pw[r] = (short)bf16b(__builtin_exp2f(sacc[tn][r] - mrun));
      const int blk = (2 * tn + (g >> 1)) ^ (c & 7);
      *(s16x4*)&psw[c * 64 + blk * 8 + (g & 1) * 4] = pw;
    }
    // --- PV + row-sum MFMA ---
    const short* ps = (const short*)Ps[wid];
    __builtin_amdgcn_s_setprio(1);
#pragma unroll
    for (int ks2 = 0; ks2 < 2; ++ks2) {
      short8 ap, bv[4];
      ap = *(const short8*)&ps[c * 64 + (((ks2 * 4 + g) ^ (c & 7)) * 8)];
      acc_l = __builtin_amdgcn_mfma_f32_16x16x32_bf16(ap, bones, acc_l, 0, 0, 0);
#pragma unroll
      for (int fe = 0; fe < 4; ++fe)
        bv[fe] = *(const short8*)&vs[(fe * 16 + c) * 64 + (((ks2 * 4 + g) ^ (c & 7)) * 8)];
#pragma unroll
      for (int fe = 0; fe < 4; ++fe)
        acc_o[fe] = __builtin_amdgcn_mfma_f32_16x16x32_bf16(ap, bv[fe], acc_o[fe], 0, 0, 0);
    }
    __builtin_amdgcn_s_setprio(0);
    __syncthreads();   // drains prefetch (vmcnt0) + publishes buffers
    cur ^= 1;
  }
  const int b = bh >> 4, h = bh & 15;
#pragma unroll
  for (int fe = 0; fe < 4; ++fe)
#pragma unroll
    for (int r = 0; r < 4; ++r) {
      const int s = q0 + wid * 16 + g * 4 + r;
      const float val = acc_o[fe][r] / acc_l[r];
      AO[((size_t)b * NS + s) * ND + h * NE + fe * 16 + c] = __float2bfloat16(val);
    }
}

// ---------------------------------------------------------------------------
// Output projection, 2-phase double-buffered, conflict-free swizzle,
// T1 XCD-contiguous remap. grid (8, 32).
// ---------------------------------------------------------------------------
__global__ __launch_bounds__(256) void proj_gemm(const bf16* __restrict__ A,
                                                 const bf16* __restrict__ Wp,
                                                 float* __restrict__ Y) {
  const int id = blockIdx.x + 8 * blockIdx.y;          // 0..255
  const int t = (id & 7) * 32 + (id >> 3);             // XCD-contiguous remap
  const int n0 = (t & 7) * 128, m0 = (t >> 3) * 128;
  __shared__ __align__(16) bf16 As[2][128 * 32];
  __shared__ __align__(16) bf16 Bs[2][128 * 32];
  const int tid = threadIdx.x;
  const int lane = tid & 63, wid = tid >> 6;
  const int wm = wid >> 1, wn = wid & 1;
  const int g = lane >> 4, c = lane & 15;
  const int row4 = tid >> 2;
  const int kcs = ((tid & 3) ^ ((tid >> 3) & 3)) * 8;

  auto stage = [&](int buf, int k0) {
    ASYNC16(A + (size_t)(m0 + row4) * ND + k0 + kcs, As[buf] + wid * 512);
    ASYNC16(A + (size_t)(m0 + 64 + row4) * ND + k0 + kcs, As[buf] + 2048 + wid * 512);
    ASYNC16(Wp + (size_t)(n0 + row4) * ND + k0 + kcs, Bs[buf] + wid * 512);
    ASYNC16(Wp + (size_t)(n0 + 64 + row4) * ND + k0 + kcs, Bs[buf] + 2048 + wid * 512);
  };

  f32x4 acc[4][4] = {};
  stage(0, 0);
  __syncthreads();
  int cur = 0;
  for (int k0 = 0; k0 < ND; k0 += 32) {
    if (k0 + 32 < ND) stage(cur ^ 1, k0 + 32);
    const short* as = (const short*)As[cur];
    const short* bs = (const short*)Bs[cur];
    short8 af[4], bq[4];
#pragma unroll
    for (int i = 0; i < 4; ++i)
      af[i] = *(const short8*)&as[(wm * 64 + i * 16 + c) * 32 + ((g ^ ((c >> 1) & 3)) * 8)];
#pragma unroll
    for (int j = 0; j < 4; ++j)
      bq[j] = *(const short8*)&bs[(wn * 64 + j * 16 + c) * 32 + ((g ^ ((c >> 1) & 3)) * 8)];
    __builtin_amdgcn_s_setprio(1);
#pragma unroll
    for (int i = 0; i < 4; ++i)
#pragma unroll
      for (int j = 0; j < 4; ++j)
        acc[i][j] = __builtin_amdgcn_mfma_f32_16x16x32_bf16(af[i], bq[j], acc[i][j], 0, 0, 0);
    __builtin_amdgcn_s_setprio(0);
    __syncthreads();
    cur ^= 1;
  }
#pragma unroll
  for (int i = 0; i < 4; ++i) {
    const int mg0 = m0 + wm * 64 + i * 16 + g * 4;
#pragma unroll
    for (int j = 0; j < 4; ++j) {
      const int ng = n0 + wn * 64 + j * 16 + c;
#pragma unroll
      for (int r = 0; r < 4; ++r)
        Y[(size_t)(mg0 + r) * ND + ng] = acc[i][j][r];
    }
  }
}

extern "C" void kernel_launch(void* const* d_in, const int* in_sizes, int n_in,
                              void* d_out, int out_size, void* d_ws, size_t ws_size,
                              hipStream_t stream) {
  const float* x  = (const float*)d_in[0];
  const float* Wq = (const float*)d_in[1];
  const float* Wk = (const float*)d_in[2];
  const float* Wv = (const float*)d_in[3];
  const float* Wp = (const float*)d_in[4];
  float* out = (float*)d_out;            // f32 output (round-7 verified)

  bf16* ws = (bf16*)d_ws;
  bf16* Xb  = ws;                                   // B*S*D     4,194,304
  bf16* WT  = Xb + (size_t)NB * NS * ND;            // 3*H*E*D   3,145,728
  bf16* Wpb = WT + (size_t)3 * NH * NE * ND;        // D*D       1,048,576
  bf16* Qb  = Wpb + (size_t)ND * ND;                // B*H*S*E   4,194,304 each
  bf16* Kb  = Qb + (size_t)NB * NH * NS * NE;
  bf16* Vt  = Kb + (size_t)NB * NH * NS * NE;
  bf16* AO  = Vt + (size_t)NB * NH * NS * NE;

  hipLaunchKernelGGL(prep_all, dim3(3328), dim3(256), 0, stream,
                     x, Xb, Wp, Wpb, Wq, Wk, Wv, WT);
  hipLaunchKernelGGL(qkv_gemm, dim3(8, 32, 3), dim3(256), 0, stream, Xb, WT, Qb, Kb, Vt);
  hipLaunchKernelGGL(attn_fwd, dim3(32, 32), dim3(256), 0, stream, Qb, Kb, Vt, AO);
  hipLaunchKernelGGL(proj_gemm, dim3(8, 32), dim3(256), 0, stream, AO, Wpb, out);
}